// Round 17
// baseline (17.736 us; speedup 1.0000x reference)
//
#include <hip/hip_runtime.h>

// Depth-4 path signature, N=64, L=512, C=8. Output/batch:
// [sig1(8) | sig2(64) | sig3(512) | sig4(4096)] = 4680 f32.
//
// R17 = R16 (17.0us) + LDS instruction-count reduction in phases B/C/reduce:
//  * lvl3 slot stride 65 -> 66 (float2 alignment for all pair reads).
//  * Phase B fold: 9 -> 6 LDS instrs (b1k/b2jk/b3 as float2).
//  * Phase C: 40 scalar reads -> 2+4 uniform b128 + 8 float2, unrolled
//    static-indexed local arrays.
//  * Reduce: 256 threads x float4 (conflict-free tiled) + stride-17
//    transpose write; was 1024 threads x 16 scalar reads.
// Spill discipline kept: #pragma unroll 4 on phase A + waves_per_eu(4,4).

static constexpr int L = 512;
static constexpr int NC = 8;
static constexpr int SIG = 8 + 64 + 512 + 4096;    // 4680
static constexpr int DXF = 4096;                   // 511*8 zero-padded
static constexpr int SLOTOFF = DXF;                // 4096
static constexpr int SLOT = 600;                   // 8 + 64 + 8*66
static constexpr int CONTRIB = SLOTOFF + 16 * SLOT;  // 13696
static constexpr int TRANSO = CONTRIB + 16 * 1024;   // 30080
static constexpr int LDSF = TRANSO + 64 * 17 + 16;   // 31184 floats
static constexpr size_t LDS_BYTES = (size_t)LDSF * sizeof(float);  // ~122 KB

template <int KQ>
__device__ __forceinline__ void sig_body(float* lds, const float* __restrict__ path,
                                         float* __restrict__ out, const int tid,
                                         const int n) {
    const int w = tid >> 6;          // wave = chunk 0..15
    const int lane = tid & 63;       // (i,j)
    const int i = lane >> 3;
    const int j = lane & 7;

    // ---- stage dx into LDS (independent parallel loads) + zero pad ----
    {
        const float4* pv = reinterpret_cast<const float4*>(path + (size_t)n * (L * NC));
        if (tid < 1022) {
            const float4 a = pv[tid];
            const float4 b = pv[tid + 2];
            *reinterpret_cast<float4*>(&lds[tid * 4]) =
                make_float4(b.x - a.x, b.y - a.y, b.z - a.z, b.w - a.w);
        } else if (tid < 1024) {
            *reinterpret_cast<float4*>(&lds[tid * 4]) = make_float4(0.f, 0.f, 0.f, 0.f);
        }
    }
    __syncthreads();

    // ---------------- Phase A: branch-free chunk scan (LDS-fed) ----------
    float s1 = 0.f, s2 = 0.f, s3a = 0.f, s3b = 0.f;
    float s3[8];
    float accA[8], accB[8];
#pragma unroll
    for (int k = 0; k < 8; ++k) {
        s3[k] = 0.f;
        accA[k] = 0.f;
        accB[k] = 0.f;
    }
    constexpr float c3 = 1.f / 6.f;
    constexpr float c4 = 1.f / 24.f;

    const float* dbase = lds + (w * 32) * 8;
    const float* bI = dbase + i;   // per-lane di base: 8 addrs, 8 banks, broadcast
    const float* bJ = dbase + j;   // per-lane dj base
#pragma unroll 4
    for (int s = 0; s < 32; ++s) {
        const float4 A = *reinterpret_cast<const float4*>(dbase + s * 8);
        const float4 B = *reinterpret_cast<const float4*>(dbase + s * 8 + 4);
        const float di = bI[s * 8];
        const float dj = bJ[s * 8];
        const float d0 = A.x, d1 = A.y, d2 = A.z, d3 = A.w;
        const float d4 = B.x, d5 = B.y, d6 = B.z, d7 = B.w;
        const float dk0 = (KQ == 0) ? d0 : (KQ == 1) ? d2 : (KQ == 2) ? d4 : d6;
        const float dk1 = (KQ == 0) ? d1 : (KQ == 1) ? d3 : (KQ == 2) ? d5 : d7;

        const float u = fmaf(s1, c3, di * c4);    // s1/6 + di/24
        float vv = fmaf(s1, dj * 0.5f, s2);       // s2 + s1*dj/2
        vv = fmaf(di * dj, c3, vv);               // + di*dj/6
        const float w_ = fmaf(s2, 0.5f, dj * u);  // s2/2 + dj*u

        const float Cc0 = fmaf(dk0, w_, s3a);     // uses OLD s3 slice
        const float Cc1 = fmaf(dk1, w_, s3b);

        accA[0] = fmaf(d0, Cc0, accA[0]);  accB[0] = fmaf(d0, Cc1, accB[0]);
        accA[1] = fmaf(d1, Cc0, accA[1]);  accB[1] = fmaf(d1, Cc1, accB[1]);
        accA[2] = fmaf(d2, Cc0, accA[2]);  accB[2] = fmaf(d2, Cc1, accB[2]);
        accA[3] = fmaf(d3, Cc0, accA[3]);  accB[3] = fmaf(d3, Cc1, accB[3]);
        accA[4] = fmaf(d4, Cc0, accA[4]);  accB[4] = fmaf(d4, Cc1, accB[4]);
        accA[5] = fmaf(d5, Cc0, accA[5]);  accB[5] = fmaf(d5, Cc1, accB[5]);
        accA[6] = fmaf(d6, Cc0, accA[6]);  accB[6] = fmaf(d6, Cc1, accB[6]);
        accA[7] = fmaf(d7, Cc0, accA[7]);  accB[7] = fmaf(d7, Cc1, accB[7]);
        s3[0] = fmaf(d0, vv, s3[0]);
        s3[1] = fmaf(d1, vv, s3[1]);
        s3[2] = fmaf(d2, vv, s3[2]);
        s3[3] = fmaf(d3, vv, s3[3]);
        s3[4] = fmaf(d4, vv, s3[4]);
        s3[5] = fmaf(d5, vv, s3[5]);
        s3[6] = fmaf(d6, vv, s3[6]);
        s3[7] = fmaf(d7, vv, s3[7]);

        s3a = fmaf(dk0, vv, s3a);
        s3b = fmaf(dk1, vv, s3b);
        s2 = fmaf(dj, fmaf(di, 0.5f, s1), s2);
        s1 += di;
    }

    // write chunk lvl1-3 to LDS slot w; lvl3 layout [t1*66 + t2*8 + t3]
    {
        float* sp = lds + SLOTOFF + w * SLOT;
        if (j == 0) sp[i] = s1;
        sp[8 + i * 8 + j] = s2;
        float* s3p = sp + 72 + i * 66 + j * 8;
#pragma unroll
        for (int m = 0; m < 4; ++m) {
            float2 t;
            t.x = s3[2 * m];
            t.y = s3[2 * m + 1];
            *reinterpret_cast<float2*>(s3p + 2 * m) = t;
        }
    }
    __syncthreads();

    // ---------------- Phase B: exclusive prefix fold (Chen, lvl1-3) ------
    float a1 = 0.f, a2 = 0.f, a3A = 0.f, a3B = 0.f;
    {
        const float* bp = lds + SLOTOFF;
        for (int b = 0; b < w; ++b, bp += SLOT) {
            const float b1i = bp[i], b1j = bp[j];
            const float2 b1k = *reinterpret_cast<const float2*>(bp + 2 * KQ);
            const float b2ij = bp[8 + i * 8 + j];
            const float2 b2jk = *reinterpret_cast<const float2*>(bp + 8 + j * 8 + 2 * KQ);
            const float2 b3 = *reinterpret_cast<const float2*>(bp + 72 + i * 66 + j * 8 + 2 * KQ);
            a3A = fmaf(a2, b1k.x, fmaf(a1, b2jk.x, a3A + b3.x));
            a3B = fmaf(a2, b1k.y, fmaf(a1, b2jk.y, a3B + b3.y));
            a2 = fmaf(a1, b1j, a2 + b2ij);
            a1 += b1i;
        }
    }

    // ---------------- Phase C: contribution -> contrib[w][c*64+lane] -----
    {
        const float* cp = lds + SLOTOFF + w * SLOT;
        float b1arr[8];
        *reinterpret_cast<float4*>(&b1arr[0]) = *reinterpret_cast<const float4*>(cp);
        *reinterpret_cast<float4*>(&b1arr[4]) = *reinterpret_cast<const float4*>(cp + 4);
        float b2arr[16];
        *reinterpret_cast<float4*>(&b2arr[0]) =
            *reinterpret_cast<const float4*>(cp + 8 + 16 * KQ);
        *reinterpret_cast<float4*>(&b2arr[4]) =
            *reinterpret_cast<const float4*>(cp + 12 + 16 * KQ);
        *reinterpret_cast<float4*>(&b2arr[8]) =
            *reinterpret_cast<const float4*>(cp + 16 + 16 * KQ);
        *reinterpret_cast<float4*>(&b2arr[12]) =
            *reinterpret_cast<const float4*>(cp + 20 + 16 * KQ);
        float b3arr[16];
        const float* b3p = cp + 72 + j * 66 + 16 * KQ;
#pragma unroll
        for (int m = 0; m < 8; ++m) {
            const float2 t = *reinterpret_cast<const float2*>(b3p + 2 * m);
            b3arr[2 * m] = t.x;
            b3arr[2 * m + 1] = t.y;
        }
        float* cb = lds + CONTRIB + w * 1024 + lane;
#pragma unroll
        for (int l = 0; l < 8; ++l) {
            const float va =
                fmaf(a3A, b1arr[l], fmaf(a2, b2arr[l], fmaf(a1, b3arr[l], accA[l])));
            const float vb = fmaf(a3B, b1arr[l],
                                  fmaf(a2, b2arr[8 + l], fmaf(a1, b3arr[8 + l], accB[l])));
            cb[l * 64] = va;          // c = 0*8 + l
            cb[(8 + l) * 64] = vb;    // c = 1*8 + l
        }
    }

    // ---------------- final lvl1-3 (wave 15; lvl3 k-slice per block) -----
    if (w == 15) {
        const float* bp = lds + SLOTOFF + 15 * SLOT;
        const float b1i = bp[i], b1j = bp[j];
        const float2 b1k = *reinterpret_cast<const float2*>(bp + 2 * KQ);
        const float b2ij = bp[8 + i * 8 + j];
        const float2 b2jk = *reinterpret_cast<const float2*>(bp + 8 + j * 8 + 2 * KQ);
        const float2 b3 = *reinterpret_cast<const float2*>(bp + 72 + i * 66 + j * 8 + 2 * KQ);
        a3A = fmaf(a2, b1k.x, fmaf(a1, b2jk.x, a3A + b3.x));
        a3B = fmaf(a2, b1k.y, fmaf(a1, b2jk.y, a3B + b3.y));
        a2 = fmaf(a1, b1j, a2 + b2ij);
        a1 += b1i;
        float* o = out + (size_t)n * SIG;
        o[72 + i * 64 + j * 8 + 2 * KQ] = a3A;
        o[72 + i * 64 + j * 8 + 2 * KQ + 1] = a3B;
        if (KQ == 0) {
            o[8 + i * 8 + j] = a2;
            if (j == 0) o[i] = a1;
        }
    }
    __syncthreads();

    // ------- reduce over w (256 thr x float4), stride-17 transpose -------
    if (tid < 256) {
        float4 s = make_float4(0.f, 0.f, 0.f, 0.f);
        const float* c0 = lds + CONTRIB + tid * 4;
#pragma unroll
        for (int ww = 0; ww < 16; ++ww) {
            const float4 v = *reinterpret_cast<const float4*>(c0 + ww * 1024);
            s.x += v.x;
            s.y += v.y;
            s.z += v.z;
            s.w += v.w;
        }
        const int c = tid >> 4;           // 0..15
        const int l0 = (tid * 4) & 63;    // 0,4,...,60
        float* tp = lds + TRANSO + c;
        tp[(l0 + 0) * 17] = s.x;
        tp[(l0 + 1) * 17] = s.y;
        tp[(l0 + 2) * 17] = s.z;
        tp[(l0 + 3) * 17] = s.w;
    }
    __syncthreads();
    if (tid < 256) {
        const int lp = tid >> 2, cq = tid & 3;
        const float* tp = lds + TRANSO + lp * 17 + cq * 4;
        float4 r;
        r.x = tp[0];
        r.y = tp[1];
        r.z = tp[2];
        r.w = tp[3];
        *reinterpret_cast<float4*>(out + (size_t)n * SIG + 584 + lp * 64 + KQ * 16 + cq * 4) = r;
    }
}

__global__ __launch_bounds__(1024)
__attribute__((amdgpu_waves_per_eu(4, 4)))
void sig_r17(const float* __restrict__ path, float* __restrict__ out) {
    extern __shared__ __align__(16) float lds[];
    const int tid = threadIdx.x;
    const int n = blockIdx.x >> 2;
    switch (blockIdx.x & 3) {
        case 0: sig_body<0>(lds, path, out, tid, n); break;
        case 1: sig_body<1>(lds, path, out, tid, n); break;
        case 2: sig_body<2>(lds, path, out, tid, n); break;
        default: sig_body<3>(lds, path, out, tid, n); break;
    }
}

extern "C" void kernel_launch(void* const* d_in, const int* in_sizes, int n_in,
                              void* d_out, int out_size, void* d_ws, size_t ws_size,
                              hipStream_t stream) {
    const float* path = (const float*)d_in[0];
    float* out = (float*)d_out;
    (void)hipFuncSetAttribute((const void*)sig_r17,
                              hipFuncAttributeMaxDynamicSharedMemorySize,
                              (int)LDS_BYTES);
    // 64 batches x 4 k-quarters = 256 blocks (1 per CU), 1024 threads each
    sig_r17<<<256, 1024, LDS_BYTES, stream>>>(path, out);
}

// Round 18
// 16.950 us; speedup vs baseline: 1.0464x; 1.0464x over previous
//
#include <hip/hip_runtime.h>

// Depth-4 path signature, N=64, L=512, C=8. Output/batch:
// [sig1(8) | sig2(64) | sig3(512) | sig4(4096)] = 4680 f32.
//
// R18 = R16 (16.98us, best) + two isolated changes:
//  1. Wave-local staging: each wave stages ONLY its own 256-float dx window
//     (lane computes one float4 diff, ds_write_b128 to own window; LDS pipe
//     is in-order per wave; compiler fenced with "memory" clobber). First
//     block-wide __syncthreads removed; waves start phase A as soon as
//     their own 2 global loads land.
//  2. Reduce phase: 256 threads x ds_read_b128 tiled (was 1024 x 16 scalar)
//     + stride-17 transpose write; 12 waves skip to the barrier.
// Everything else byte-identical to R16 (phase A ds-broadcast di/dj,
// template<KQ>, SLOT stride 65, scalar phase B/C reads).
// Spill discipline: #pragma unroll 4 on phase A + waves_per_eu(4,4).

static constexpr int L = 512;
static constexpr int NC = 8;
static constexpr int SIG = 8 + 64 + 512 + 4096;    // 4680
static constexpr int DXF = 4096;                   // 511*8 zero-padded
static constexpr int SLOTOFF = DXF;                // 4096
static constexpr int SLOT = 592;                   // 8 + 64 + 520 (lvl3 stride 65)
static constexpr int CONTRIB = SLOTOFF + 16 * SLOT;  // 13568
static constexpr int TRANSO = CONTRIB + 16 * 1024;   // 29952
static constexpr int LDSF = TRANSO + 64 * 17 + 16;   // 31056 floats
static constexpr size_t LDS_BYTES = (size_t)LDSF * sizeof(float);  // ~121 KB

template <int KQ>
__device__ __forceinline__ void sig_body(float* lds, const float* __restrict__ path,
                                         float* __restrict__ out, const int tid,
                                         const int n) {
    const int w = tid >> 6;          // wave = chunk 0..15
    const int lane = tid & 63;       // (i,j)
    const int i = lane >> 3;
    const int j = lane & 7;

    // ---- wave-local staging: own 256-float dx window, NO block barrier ----
    {
        const float4* pv = reinterpret_cast<const float4*>(path + (size_t)n * (L * NC));
        const int base = w * 64 + lane;              // float4 index, 0..1023
        const float4 a = pv[base];
        const float4 b = pv[min(base + 2, 1023)];
        float4 d;
        d.x = b.x - a.x;
        d.y = b.y - a.y;
        d.z = b.z - a.z;
        d.w = b.w - a.w;
        if (base >= 1022) d = make_float4(0.f, 0.f, 0.f, 0.f);  // seg 511 pad
        *reinterpret_cast<float4*>(&lds[base * 4]) = d;
        asm volatile("" ::: "memory");  // no reordering of phase-A reads above this
    }

    // ---------------- Phase A: branch-free chunk scan (LDS-fed) ----------
    float s1 = 0.f, s2 = 0.f, s3a = 0.f, s3b = 0.f;
    float s3[8];
    float accA[8], accB[8];
#pragma unroll
    for (int k = 0; k < 8; ++k) {
        s3[k] = 0.f;
        accA[k] = 0.f;
        accB[k] = 0.f;
    }
    constexpr float c3 = 1.f / 6.f;
    constexpr float c4 = 1.f / 24.f;

    const float* dbase = lds + (w * 32) * 8;   // own window only
    const float* bI = dbase + i;   // per-lane di base: 8 addrs, 8 banks, broadcast
    const float* bJ = dbase + j;   // per-lane dj base
#pragma unroll 4
    for (int s = 0; s < 32; ++s) {
        const float4 A = *reinterpret_cast<const float4*>(dbase + s * 8);
        const float4 B = *reinterpret_cast<const float4*>(dbase + s * 8 + 4);
        const float di = bI[s * 8];
        const float dj = bJ[s * 8];
        const float d0 = A.x, d1 = A.y, d2 = A.z, d3 = A.w;
        const float d4 = B.x, d5 = B.y, d6 = B.z, d7 = B.w;
        const float dk0 = (KQ == 0) ? d0 : (KQ == 1) ? d2 : (KQ == 2) ? d4 : d6;
        const float dk1 = (KQ == 0) ? d1 : (KQ == 1) ? d3 : (KQ == 2) ? d5 : d7;

        const float u = fmaf(s1, c3, di * c4);    // s1/6 + di/24
        float vv = fmaf(s1, dj * 0.5f, s2);       // s2 + s1*dj/2
        vv = fmaf(di * dj, c3, vv);               // + di*dj/6
        const float w_ = fmaf(s2, 0.5f, dj * u);  // s2/2 + dj*u

        const float Cc0 = fmaf(dk0, w_, s3a);     // uses OLD s3 slice
        const float Cc1 = fmaf(dk1, w_, s3b);

        accA[0] = fmaf(d0, Cc0, accA[0]);  accB[0] = fmaf(d0, Cc1, accB[0]);
        accA[1] = fmaf(d1, Cc0, accA[1]);  accB[1] = fmaf(d1, Cc1, accB[1]);
        accA[2] = fmaf(d2, Cc0, accA[2]);  accB[2] = fmaf(d2, Cc1, accB[2]);
        accA[3] = fmaf(d3, Cc0, accA[3]);  accB[3] = fmaf(d3, Cc1, accB[3]);
        accA[4] = fmaf(d4, Cc0, accA[4]);  accB[4] = fmaf(d4, Cc1, accB[4]);
        accA[5] = fmaf(d5, Cc0, accA[5]);  accB[5] = fmaf(d5, Cc1, accB[5]);
        accA[6] = fmaf(d6, Cc0, accA[6]);  accB[6] = fmaf(d6, Cc1, accB[6]);
        accA[7] = fmaf(d7, Cc0, accA[7]);  accB[7] = fmaf(d7, Cc1, accB[7]);
        s3[0] = fmaf(d0, vv, s3[0]);
        s3[1] = fmaf(d1, vv, s3[1]);
        s3[2] = fmaf(d2, vv, s3[2]);
        s3[3] = fmaf(d3, vv, s3[3]);
        s3[4] = fmaf(d4, vv, s3[4]);
        s3[5] = fmaf(d5, vv, s3[5]);
        s3[6] = fmaf(d6, vv, s3[6]);
        s3[7] = fmaf(d7, vv, s3[7]);

        s3a = fmaf(dk0, vv, s3a);
        s3b = fmaf(dk1, vv, s3b);
        s2 = fmaf(dj, fmaf(di, 0.5f, s1), s2);
        s1 += di;
    }

    // write chunk lvl1-3 to LDS slot w; lvl3 layout [t1*65 + t2*8 + t3]
    {
        float* sp = lds + SLOTOFF + w * SLOT;
        if (j == 0) sp[i] = s1;
        sp[8 + i * 8 + j] = s2;
        float* s3p = sp + 72 + i * 65 + j * 8;
#pragma unroll
        for (int k = 0; k < 8; ++k) s3p[k] = s3[k];
    }
    __syncthreads();

    // ---------------- Phase B: exclusive prefix fold (Chen, lvl1-3) ------
    float a1 = 0.f, a2 = 0.f, a3A = 0.f, a3B = 0.f;
    {
        const float* bp = lds + SLOTOFF;
        for (int b = 0; b < w; ++b, bp += SLOT) {
            const float b1i = bp[i], b1j = bp[j];
            const float b1k0 = bp[2 * KQ], b1k1 = bp[2 * KQ + 1];
            const float b2ij = bp[8 + i * 8 + j];
            const float b2jk0 = bp[8 + j * 8 + 2 * KQ];
            const float b2jk1 = bp[8 + j * 8 + 2 * KQ + 1];
            const float b3a = bp[72 + i * 65 + j * 8 + 2 * KQ];
            const float b3b = bp[72 + i * 65 + j * 8 + 2 * KQ + 1];
            a3A = fmaf(a2, b1k0, fmaf(a1, b2jk0, a3A + b3a));
            a3B = fmaf(a2, b1k1, fmaf(a1, b2jk1, a3B + b3b));
            a2 = fmaf(a1, b1j, a2 + b2ij);
            a1 += b1i;
        }
    }

    // ---------------- Phase C: contribution -> contrib[w][c*64+lane] -----
    {
        const float* cp = lds + SLOTOFF + w * SLOT;
        float* cb = lds + CONTRIB + w * 1024 + lane;
#pragma unroll
        for (int l = 0; l < 8; ++l) {
            const float b1l = cp[l];
            const float b2a = cp[8 + 16 * KQ + l];
            const float b2b = cp[8 + 16 * KQ + 8 + l];
            const float b3a = cp[72 + j * 65 + 16 * KQ + l];
            const float b3b = cp[72 + j * 65 + 16 * KQ + 8 + l];
            const float va = fmaf(a3A, b1l, fmaf(a2, b2a, fmaf(a1, b3a, accA[l])));
            const float vb = fmaf(a3B, b1l, fmaf(a2, b2b, fmaf(a1, b3b, accB[l])));
            cb[l * 64] = va;          // c = 0*8 + l
            cb[(8 + l) * 64] = vb;    // c = 1*8 + l
        }
    }

    // ---------------- final lvl1-3 (wave 15; lvl3 k-slice per block) -----
    if (w == 15) {
        const float* bp = lds + SLOTOFF + 15 * SLOT;
        const float b1i = bp[i], b1j = bp[j];
        const float b1k0 = bp[2 * KQ], b1k1 = bp[2 * KQ + 1];
        const float b2ij = bp[8 + i * 8 + j];
        const float b2jk0 = bp[8 + j * 8 + 2 * KQ];
        const float b2jk1 = bp[8 + j * 8 + 2 * KQ + 1];
        const float b3a = bp[72 + i * 65 + j * 8 + 2 * KQ];
        const float b3b = bp[72 + i * 65 + j * 8 + 2 * KQ + 1];
        a3A = fmaf(a2, b1k0, fmaf(a1, b2jk0, a3A + b3a));
        a3B = fmaf(a2, b1k1, fmaf(a1, b2jk1, a3B + b3b));
        a2 = fmaf(a1, b1j, a2 + b2ij);
        a1 += b1i;
        float* o = out + (size_t)n * SIG;
        o[72 + i * 64 + j * 8 + 2 * KQ] = a3A;
        o[72 + i * 64 + j * 8 + 2 * KQ + 1] = a3B;
        if (KQ == 0) {
            o[8 + i * 8 + j] = a2;
            if (j == 0) o[i] = a1;
        }
    }
    __syncthreads();

    // ------- reduce over w (256 thr x ds_read_b128), stride-17 transpose --
    if (tid < 256) {
        float4 s = make_float4(0.f, 0.f, 0.f, 0.f);
        const float* c0 = lds + CONTRIB + tid * 4;
#pragma unroll
        for (int ww = 0; ww < 16; ++ww) {
            const float4 v = *reinterpret_cast<const float4*>(c0 + ww * 1024);
            s.x += v.x;
            s.y += v.y;
            s.z += v.z;
            s.w += v.w;
        }
        const int c = tid >> 4;           // chunk col 0..15
        const int l0 = (tid * 4) & 63;    // lane row base 0,4,...,60
        float* tp = lds + TRANSO + c;
        tp[(l0 + 0) * 17] = s.x;
        tp[(l0 + 1) * 17] = s.y;
        tp[(l0 + 2) * 17] = s.z;
        tp[(l0 + 3) * 17] = s.w;
    }
    __syncthreads();
    if (tid < 256) {
        const int lp = tid >> 2, cq = tid & 3;
        const float* tp = lds + TRANSO + lp * 17 + cq * 4;
        float4 r;
        r.x = tp[0];
        r.y = tp[1];
        r.z = tp[2];
        r.w = tp[3];
        *reinterpret_cast<float4*>(out + (size_t)n * SIG + 584 + lp * 64 + KQ * 16 + cq * 4) = r;
    }
}

__global__ __launch_bounds__(1024)
__attribute__((amdgpu_waves_per_eu(4, 4)))
void sig_r18(const float* __restrict__ path, float* __restrict__ out) {
    extern __shared__ __align__(16) float lds[];
    const int tid = threadIdx.x;
    const int n = blockIdx.x >> 2;
    switch (blockIdx.x & 3) {
        case 0: sig_body<0>(lds, path, out, tid, n); break;
        case 1: sig_body<1>(lds, path, out, tid, n); break;
        case 2: sig_body<2>(lds, path, out, tid, n); break;
        default: sig_body<3>(lds, path, out, tid, n); break;
    }
}

extern "C" void kernel_launch(void* const* d_in, const int* in_sizes, int n_in,
                              void* d_out, int out_size, void* d_ws, size_t ws_size,
                              hipStream_t stream) {
    const float* path = (const float*)d_in[0];
    float* out = (float*)d_out;
    (void)hipFuncSetAttribute((const void*)sig_r18,
                              hipFuncAttributeMaxDynamicSharedMemorySize,
                              (int)LDS_BYTES);
    // 64 batches x 4 k-quarters = 256 blocks (1 per CU), 1024 threads each
    sig_r18<<<256, 1024, LDS_BYTES, stream>>>(path, out);
}

// Round 19
// 16.337 us; speedup vs baseline: 1.0857x; 1.0375x over previous
//
#include <hip/hip_runtime.h>

// Depth-4 path signature, N=64, L=512, C=8. Output/batch:
// [sig1(8) | sig2(64) | sig3(512) | sig4(4096)] = 4680 f32.
//
// R19 = R18 (16.95us, best) + phase-A VALU-count cut (single mechanism):
//  * s3a/s3b deleted: they duplicated s3[2KQ]/s3[2KQ+1] exactly (same FMA
//    recurrence); with compile-time KQ the Cc coefficients read the OLD
//    s3[2KQ]/[2KQ+1] directly (computed before the s3 update block).
//    -2 FMA/step, -2 VGPR.
//  * vv re-associated: s2 + dj*(s1/2 + di/6) = 3 ops (was 4).
// Everything else byte-identical to R18: wave-local staging (no first
// barrier), ds-broadcast di/dj, template<KQ>, scalar B/C, float4 reduce.
// Spill discipline: #pragma unroll 4 + waves_per_eu(4,4).

static constexpr int L = 512;
static constexpr int NC = 8;
static constexpr int SIG = 8 + 64 + 512 + 4096;    // 4680
static constexpr int DXF = 4096;                   // 511*8 zero-padded
static constexpr int SLOTOFF = DXF;                // 4096
static constexpr int SLOT = 592;                   // 8 + 64 + 520 (lvl3 stride 65)
static constexpr int CONTRIB = SLOTOFF + 16 * SLOT;  // 13568
static constexpr int TRANSO = CONTRIB + 16 * 1024;   // 29952
static constexpr int LDSF = TRANSO + 64 * 17 + 16;   // 31056 floats
static constexpr size_t LDS_BYTES = (size_t)LDSF * sizeof(float);  // ~121 KB

template <int KQ>
__device__ __forceinline__ void sig_body(float* lds, const float* __restrict__ path,
                                         float* __restrict__ out, const int tid,
                                         const int n) {
    const int w = tid >> 6;          // wave = chunk 0..15
    const int lane = tid & 63;       // (i,j)
    const int i = lane >> 3;
    const int j = lane & 7;

    // ---- wave-local staging: own 256-float dx window, NO block barrier ----
    {
        const float4* pv = reinterpret_cast<const float4*>(path + (size_t)n * (L * NC));
        const int base = w * 64 + lane;              // float4 index, 0..1023
        const float4 a = pv[base];
        const float4 b = pv[min(base + 2, 1023)];
        float4 d;
        d.x = b.x - a.x;
        d.y = b.y - a.y;
        d.z = b.z - a.z;
        d.w = b.w - a.w;
        if (base >= 1022) d = make_float4(0.f, 0.f, 0.f, 0.f);  // seg 511 pad
        *reinterpret_cast<float4*>(&lds[base * 4]) = d;
        asm volatile("" ::: "memory");  // no reordering of phase-A reads above this
    }

    // ---------------- Phase A: branch-free chunk scan (LDS-fed) ----------
    float s1 = 0.f, s2 = 0.f;
    float s3[8];
    float accA[8], accB[8];
#pragma unroll
    for (int k = 0; k < 8; ++k) {
        s3[k] = 0.f;
        accA[k] = 0.f;
        accB[k] = 0.f;
    }
    constexpr float c3 = 1.f / 6.f;
    constexpr float c4 = 1.f / 24.f;

    const float* dbase = lds + (w * 32) * 8;   // own window only
    const float* bI = dbase + i;   // per-lane di base: 8 addrs, 8 banks, broadcast
    const float* bJ = dbase + j;   // per-lane dj base
#pragma unroll 4
    for (int s = 0; s < 32; ++s) {
        const float4 A = *reinterpret_cast<const float4*>(dbase + s * 8);
        const float4 B = *reinterpret_cast<const float4*>(dbase + s * 8 + 4);
        const float di = bI[s * 8];
        const float dj = bJ[s * 8];
        const float d0 = A.x, d1 = A.y, d2 = A.z, d3 = A.w;
        const float d4 = B.x, d5 = B.y, d6 = B.z, d7 = B.w;
        const float dk0 = (KQ == 0) ? d0 : (KQ == 1) ? d2 : (KQ == 2) ? d4 : d6;
        const float dk1 = (KQ == 0) ? d1 : (KQ == 1) ? d3 : (KQ == 2) ? d5 : d7;

        const float u = fmaf(s1, c3, di * c4);            // s1/6 + di/24
        const float vv = fmaf(dj, fmaf(di, c3, s1 * 0.5f), s2);  // s2+dj*(s1/2+di/6)
        const float w_ = fmaf(s2, 0.5f, dj * u);          // s2/2 + dj*u

        // Cc from OLD s3 slice (s3[2KQ] not yet updated this step)
        const float Cc0 = fmaf(dk0, w_, s3[2 * KQ]);
        const float Cc1 = fmaf(dk1, w_, s3[2 * KQ + 1]);

        accA[0] = fmaf(d0, Cc0, accA[0]);  accB[0] = fmaf(d0, Cc1, accB[0]);
        accA[1] = fmaf(d1, Cc0, accA[1]);  accB[1] = fmaf(d1, Cc1, accB[1]);
        accA[2] = fmaf(d2, Cc0, accA[2]);  accB[2] = fmaf(d2, Cc1, accB[2]);
        accA[3] = fmaf(d3, Cc0, accA[3]);  accB[3] = fmaf(d3, Cc1, accB[3]);
        accA[4] = fmaf(d4, Cc0, accA[4]);  accB[4] = fmaf(d4, Cc1, accB[4]);
        accA[5] = fmaf(d5, Cc0, accA[5]);  accB[5] = fmaf(d5, Cc1, accB[5]);
        accA[6] = fmaf(d6, Cc0, accA[6]);  accB[6] = fmaf(d6, Cc1, accB[6]);
        accA[7] = fmaf(d7, Cc0, accA[7]);  accB[7] = fmaf(d7, Cc1, accB[7]);
        s3[0] = fmaf(d0, vv, s3[0]);
        s3[1] = fmaf(d1, vv, s3[1]);
        s3[2] = fmaf(d2, vv, s3[2]);
        s3[3] = fmaf(d3, vv, s3[3]);
        s3[4] = fmaf(d4, vv, s3[4]);
        s3[5] = fmaf(d5, vv, s3[5]);
        s3[6] = fmaf(d6, vv, s3[6]);
        s3[7] = fmaf(d7, vv, s3[7]);

        s2 = fmaf(dj, fmaf(di, 0.5f, s1), s2);
        s1 += di;
    }

    // write chunk lvl1-3 to LDS slot w; lvl3 layout [t1*65 + t2*8 + t3]
    {
        float* sp = lds + SLOTOFF + w * SLOT;
        if (j == 0) sp[i] = s1;
        sp[8 + i * 8 + j] = s2;
        float* s3p = sp + 72 + i * 65 + j * 8;
#pragma unroll
        for (int k = 0; k < 8; ++k) s3p[k] = s3[k];
    }
    __syncthreads();

    // ---------------- Phase B: exclusive prefix fold (Chen, lvl1-3) ------
    float a1 = 0.f, a2 = 0.f, a3A = 0.f, a3B = 0.f;
    {
        const float* bp = lds + SLOTOFF;
        for (int b = 0; b < w; ++b, bp += SLOT) {
            const float b1i = bp[i], b1j = bp[j];
            const float b1k0 = bp[2 * KQ], b1k1 = bp[2 * KQ + 1];
            const float b2ij = bp[8 + i * 8 + j];
            const float b2jk0 = bp[8 + j * 8 + 2 * KQ];
            const float b2jk1 = bp[8 + j * 8 + 2 * KQ + 1];
            const float b3a = bp[72 + i * 65 + j * 8 + 2 * KQ];
            const float b3b = bp[72 + i * 65 + j * 8 + 2 * KQ + 1];
            a3A = fmaf(a2, b1k0, fmaf(a1, b2jk0, a3A + b3a));
            a3B = fmaf(a2, b1k1, fmaf(a1, b2jk1, a3B + b3b));
            a2 = fmaf(a1, b1j, a2 + b2ij);
            a1 += b1i;
        }
    }

    // ---------------- Phase C: contribution -> contrib[w][c*64+lane] -----
    {
        const float* cp = lds + SLOTOFF + w * SLOT;
        float* cb = lds + CONTRIB + w * 1024 + lane;
#pragma unroll
        for (int l = 0; l < 8; ++l) {
            const float b1l = cp[l];
            const float b2a = cp[8 + 16 * KQ + l];
            const float b2b = cp[8 + 16 * KQ + 8 + l];
            const float b3a = cp[72 + j * 65 + 16 * KQ + l];
            const float b3b = cp[72 + j * 65 + 16 * KQ + 8 + l];
            const float va = fmaf(a3A, b1l, fmaf(a2, b2a, fmaf(a1, b3a, accA[l])));
            const float vb = fmaf(a3B, b1l, fmaf(a2, b2b, fmaf(a1, b3b, accB[l])));
            cb[l * 64] = va;          // c = 0*8 + l
            cb[(8 + l) * 64] = vb;    // c = 1*8 + l
        }
    }

    // ---------------- final lvl1-3 (wave 15; lvl3 k-slice per block) -----
    if (w == 15) {
        const float* bp = lds + SLOTOFF + 15 * SLOT;
        const float b1i = bp[i], b1j = bp[j];
        const float b1k0 = bp[2 * KQ], b1k1 = bp[2 * KQ + 1];
        const float b2ij = bp[8 + i * 8 + j];
        const float b2jk0 = bp[8 + j * 8 + 2 * KQ];
        const float b2jk1 = bp[8 + j * 8 + 2 * KQ + 1];
        const float b3a = bp[72 + i * 65 + j * 8 + 2 * KQ];
        const float b3b = bp[72 + i * 65 + j * 8 + 2 * KQ + 1];
        a3A = fmaf(a2, b1k0, fmaf(a1, b2jk0, a3A + b3a));
        a3B = fmaf(a2, b1k1, fmaf(a1, b2jk1, a3B + b3b));
        a2 = fmaf(a1, b1j, a2 + b2ij);
        a1 += b1i;
        float* o = out + (size_t)n * SIG;
        o[72 + i * 64 + j * 8 + 2 * KQ] = a3A;
        o[72 + i * 64 + j * 8 + 2 * KQ + 1] = a3B;
        if (KQ == 0) {
            o[8 + i * 8 + j] = a2;
            if (j == 0) o[i] = a1;
        }
    }
    __syncthreads();

    // ------- reduce over w (256 thr x ds_read_b128), stride-17 transpose --
    if (tid < 256) {
        float4 s = make_float4(0.f, 0.f, 0.f, 0.f);
        const float* c0 = lds + CONTRIB + tid * 4;
#pragma unroll
        for (int ww = 0; ww < 16; ++ww) {
            const float4 v = *reinterpret_cast<const float4*>(c0 + ww * 1024);
            s.x += v.x;
            s.y += v.y;
            s.z += v.z;
            s.w += v.w;
        }
        const int c = tid >> 4;           // chunk col 0..15
        const int l0 = (tid * 4) & 63;    // lane row base 0,4,...,60
        float* tp = lds + TRANSO + c;
        tp[(l0 + 0) * 17] = s.x;
        tp[(l0 + 1) * 17] = s.y;
        tp[(l0 + 2) * 17] = s.z;
        tp[(l0 + 3) * 17] = s.w;
    }
    __syncthreads();
    if (tid < 256) {
        const int lp = tid >> 2, cq = tid & 3;
        const float* tp = lds + TRANSO + lp * 17 + cq * 4;
        float4 r;
        r.x = tp[0];
        r.y = tp[1];
        r.z = tp[2];
        r.w = tp[3];
        *reinterpret_cast<float4*>(out + (size_t)n * SIG + 584 + lp * 64 + KQ * 16 + cq * 4) = r;
    }
}

__global__ __launch_bounds__(1024)
__attribute__((amdgpu_waves_per_eu(4, 4)))
void sig_r19(const float* __restrict__ path, float* __restrict__ out) {
    extern __shared__ __align__(16) float lds[];
    const int tid = threadIdx.x;
    const int n = blockIdx.x >> 2;
    switch (blockIdx.x & 3) {
        case 0: sig_body<0>(lds, path, out, tid, n); break;
        case 1: sig_body<1>(lds, path, out, tid, n); break;
        case 2: sig_body<2>(lds, path, out, tid, n); break;
        default: sig_body<3>(lds, path, out, tid, n); break;
    }
}

extern "C" void kernel_launch(void* const* d_in, const int* in_sizes, int n_in,
                              void* d_out, int out_size, void* d_ws, size_t ws_size,
                              hipStream_t stream) {
    const float* path = (const float*)d_in[0];
    float* out = (float*)d_out;
    (void)hipFuncSetAttribute((const void*)sig_r19,
                              hipFuncAttributeMaxDynamicSharedMemorySize,
                              (int)LDS_BYTES);
    // 64 batches x 4 k-quarters = 256 blocks (1 per CU), 1024 threads each
    sig_r19<<<256, 1024, LDS_BYTES, stream>>>(path, out);
}